// Round 1
// baseline (490.661 us; speedup 1.0000x reference)
//
#include <hip/hip_runtime.h>

// LiZAttention delta-product scan, MI355X
// B=2 H=16 NC=32 CT=128 (C=64, N_ORDERS=2) D=128
// Phase 1: 32 blocks, sequential chunk scan of h (c=63 only) -> hws (bf16) + h_final
// Phase 2: 1024 blocks, per-(bh,chunk) tile: 4x [64x128]@[128x128] bf16 MFMA + epilogue

#define Dd 128
#define NCH 32
#define YS 16777216  // ys element count; h_final follows in d_out

typedef __attribute__((ext_vector_type(4))) float floatx4;
typedef __attribute__((ext_vector_type(8))) short short8;

__device__ __forceinline__ unsigned short f2bf(float f) {
  unsigned int u = __float_as_uint(f);
  u += 0x7fffu + ((u >> 16) & 1u);   // round-to-nearest-even
  return (unsigned short)(u >> 16);
}
__device__ __forceinline__ float clampf(float x) {
  return fminf(fmaxf(x, -10000.0f), 10000.0f);
}
__device__ __forceinline__ float tanh_fast(float y) {
  float e = __expf(2.0f * y);
  return (e - 1.0f) / (e + 1.0f);
}

// ---------------- Phase 1: sequential h-scan ----------------
__global__ __launch_bounds__(512) void p1_scan(const float* __restrict__ W,
    const float* __restrict__ U, const float* __restrict__ h0,
    unsigned short* __restrict__ hws, float* __restrict__ out) {
  __shared__ float hs[Dd * Dd];                       // 64 KB fp32 state
  __shared__ float w0s[Dd], w1s[Dd], u0s[Dd], u1s[Dd];
  __shared__ float uv0s[Dd], uv1s[Dd], t1s[Dd];
  __shared__ float mv0p[4 * Dd], mv1p[4 * Dd];
  __shared__ float psum[Dd * 4];
  __shared__ float d10sh;

  const int bh = blockIdx.x;
  const int t = threadIdx.x;

  // load h0 -> LDS fp32, also emit bf16 h_0 to ws chunk 0
  {
    const float4* src = (const float4*)(h0 + bh * 16384 + 32 * t);
    float4* dst = (float4*)(hs + 32 * t);
    uint4* wdst = (uint4*)(hws + (size_t)bh * NCH * 16384 + 32 * t);
#pragma unroll
    for (int i = 0; i < 4; i++) {
      float4 a = src[2 * i], b = src[2 * i + 1];
      dst[2 * i] = a; dst[2 * i + 1] = b;
      uint4 u;
      u.x = (unsigned)f2bf(a.x) | ((unsigned)f2bf(a.y) << 16);
      u.y = (unsigned)f2bf(a.z) | ((unsigned)f2bf(a.w) << 16);
      u.z = (unsigned)f2bf(b.x) | ((unsigned)f2bf(b.y) << 16);
      u.w = (unsigned)f2bf(b.z) | ((unsigned)f2bf(b.w) << 16);
      wdst[i] = u;
    }
  }
  __syncthreads();

  const int e_mv = t & 127, dq_mv = t >> 7;  // matvec: column e, d-quarter
  const int d_up = t >> 2, eq_up = t & 3;    // update: row d, e-quarter

  for (int n = 0; n < NCH; n++) {
    const float* base_w = W + (size_t)(bh * NCH + n) * 16384;
    const float* base_u = U + (size_t)(bh * NCH + n) * 16384;
    // rows c=63: t-index 126 (step0), 127 (step1)
    if (t < 128) {
      w0s[t] = base_w[126 * Dd + t];
      u0s[t] = base_u[126 * Dd + t];
    } else if (t < 256) {
      int e = t - 128;
      w1s[e] = base_w[127 * Dd + e];
      u1s[e] = base_u[127 * Dd + e];
    }
    __syncthreads();
    // matvec partials: t0[e]=sum_d w0[d]h[d][e], t1[e]=sum_d w1[d]h[d][e]
    {
      float a0 = 0.f, a1 = 0.f;
#pragma unroll
      for (int i = 0; i < 32; i++) {
        int d = dq_mv * 32 + i;
        float v = hs[d * Dd + e_mv];
        a0 += w0s[d] * v;
        a1 += w1s[d] * v;
      }
      mv0p[dq_mv * Dd + e_mv] = a0;
      mv1p[dq_mv * Dd + e_mv] = a1;
    }
    __syncthreads();
    if (t < 128) {
      float t0 = mv0p[t] + mv0p[Dd + t] + mv0p[2 * Dd + t] + mv0p[3 * Dd + t];
      uv0s[t] = u0s[t] - t0;
    } else if (t < 256) {
      int e = t - 128;
      t1s[e] = mv1p[e] + mv1p[Dd + e] + mv1p[2 * Dd + e] + mv1p[3 * Dd + e];
    } else if (t < 320) {
      int l = t - 256;  // lanes of wave 4: d10 = w1.w0
      float p = w1s[2 * l] * w0s[2 * l] + w1s[2 * l + 1] * w0s[2 * l + 1];
#pragma unroll
      for (int off = 32; off > 0; off >>= 1) p += __shfl_xor(p, off, 64);
      if (l == 0) d10sh = p;
    }
    __syncthreads();
    if (t < 128) uv1s[t] = u1s[t] - t1s[t] - d10sh * uv0s[t];
    __syncthreads();
    // state2 = clip(clip(h + w0 (x) uv0) + w1 (x) uv1); row sum-of-squares
    float sreg[32];
    {
      float w0d = w0s[d_up], w1d = w1s[d_up];
      float sq = 0.f;
#pragma unroll
      for (int i = 0; i < 32; i++) {
        int e = eq_up * 32 + i;
        float s1 = clampf(hs[d_up * Dd + e] + w0d * uv0s[e]);
        float s2 = clampf(s1 + w1d * uv1s[e]);
        sreg[i] = s2;
        sq += s2 * s2;
      }
      psum[d_up * 4 + eq_up] = sq;
    }
    __syncthreads();
    // gelu_norm: n/2 * gelu(2h/n), tanh-approx
    {
      float nd = sqrtf(psum[d_up * 4] + psum[d_up * 4 + 1] + psum[d_up * 4 + 2] +
                       psum[d_up * 4 + 3]) + 1e-6f;
      float r2 = 2.0f / nd, half_n = 0.5f * nd;
#pragma unroll
      for (int i = 0; i < 32; i++) {
        float x = sreg[i] * r2;
        float inner = 0.7978845608f * (x + 0.044715f * x * x * x);
        float g = 0.5f * x * (1.0f + tanh_fast(inner));
        float hn = half_n * g;
        sreg[i] = hn;
        hs[d_up * Dd + eq_up * 32 + i] = hn;  // flat = 32t+i
      }
    }
    if (n < NCH - 1) {
      uint4* wdst = (uint4*)(hws + (size_t)(bh * NCH + n + 1) * 16384 + 32 * t);
#pragma unroll
      for (int i = 0; i < 4; i++) {
        uint4 u;
        u.x = (unsigned)f2bf(sreg[8 * i + 0]) | ((unsigned)f2bf(sreg[8 * i + 1]) << 16);
        u.y = (unsigned)f2bf(sreg[8 * i + 2]) | ((unsigned)f2bf(sreg[8 * i + 3]) << 16);
        u.z = (unsigned)f2bf(sreg[8 * i + 4]) | ((unsigned)f2bf(sreg[8 * i + 5]) << 16);
        u.w = (unsigned)f2bf(sreg[8 * i + 6]) | ((unsigned)f2bf(sreg[8 * i + 7]) << 16);
        wdst[i] = u;
      }
    } else {
      float4* od = (float4*)(out + YS + bh * 16384 + 32 * t);
#pragma unroll
      for (int i = 0; i < 8; i++) {
        float4 v;
        v.x = sreg[4 * i]; v.y = sreg[4 * i + 1];
        v.z = sreg[4 * i + 2]; v.w = sreg[4 * i + 3];
        od[i] = v;
      }
    }
    __syncthreads();
  }
}

// ---------------- Phase 2: per-tile outputs via MFMA ----------------
// wave w (of 8): pair p=w>>2 (0:{Q0,W0}, 1:{Q1,W1}), e-quarter eq=w&3 (etiles 2eq,2eq+1)
// 16x16x32 bf16 MFMA: A[m=lane&15][k=8*(lane>>4)+i]; B[k=8*(lane>>4)+i][n=lane&15];
//                     C/D: row=4*(lane>>4)+reg, col=lane&15   [measured m89/m91]
__global__ __launch_bounds__(512) void p2_out(const float* __restrict__ Q,
    const float* __restrict__ W, const float* __restrict__ U,
    const unsigned short* __restrict__ hws, float* __restrict__ out) {
  __shared__ unsigned short hlds[Dd * Dd];  // 32KB bf16 h; aliased as uv0 (fp32 64x128) post-matmul
  __shared__ float d10s[64], dq1s[64];
  __shared__ float dps[512];

  const int bid = blockIdx.x;
  const int n = bid & 31, bh = bid >> 5;
  const size_t base = (size_t)(bh * NCH + n) * 16384;
  const float* Qb = Q + base;
  const float* Wb = W + base;
  const float* Ub = U + base;
  float* Ob = out + base;
  const int t = threadIdx.x;

  // stage h (bf16) -> LDS, 64B per thread, contiguous
  {
    const uint4* src = (const uint4*)(hws + base) + t * 4;
    uint4* dst = (uint4*)hlds + t * 4;
#pragma unroll
    for (int i = 0; i < 4; i++) dst[i] = src[i];
  }
  // per-c dots: d10[c]=w1.w0, dq1[c]=q1.w0  (fp32 from global)
  {
    int which = t >> 8, tt = t & 255;
    int c = tt >> 2, part = tt & 3;
    const float* ar = (which ? Qb : Wb) + (2 * c + 1) * Dd + part * 32;
    const float* w0r = Wb + (2 * c) * Dd + part * 32;
    float s = 0.f;
#pragma unroll
    for (int i = 0; i < 32; i++) s += ar[i] * w0r[i];
    dps[which * 256 + tt] = s;
  }
  __syncthreads();
  if (t < 128) {
    int which = t >> 6, c = t & 63;
    const float* p = dps + which * 256 + c * 4;
    float s = p[0] + p[1] + p[2] + p[3];
    (which ? dq1s : d10s)[c] = s;
  }

  const int wv = t >> 6, l = t & 63;
  const int pr = wv >> 2, eq = wv & 3;
  const int lm = l & 15, lq = l >> 4;

  floatx4 acc[2][4][2];  // [mat 0=Q_p,1=W_p][ctile][etile]
#pragma unroll
  for (int m = 0; m < 2; m++)
#pragma unroll
    for (int ci = 0; ci < 4; ci++)
#pragma unroll
      for (int j = 0; j < 2; j++) acc[m][ci][j] = (floatx4){0.f, 0.f, 0.f, 0.f};

  for (int kc = 0; kc < 4; kc++) {
    const int k0 = kc * 32;
    union { short8 v; unsigned short u[8]; } bfr[2];
#pragma unroll
    for (int j = 0; j < 2; j++) {
      int e = (2 * eq + j) * 16 + lm;
#pragma unroll
      for (int i = 0; i < 8; i++) bfr[j].u[i] = hlds[(k0 + 8 * lq + i) * Dd + e];
    }
#pragma unroll
    for (int m = 0; m < 2; m++) {
      const float* X = m ? Wb : Qb;
#pragma unroll
      for (int ci = 0; ci < 4; ci++) {
        int c = ci * 16 + lm;
        const float* row = X + (size_t)(2 * c + pr) * Dd + k0 + 8 * lq;
        float4 f0 = ((const float4*)row)[0];
        float4 f1 = ((const float4*)row)[1];
        union { short8 v; unsigned short u[8]; } af;
        af.u[0] = f2bf(f0.x); af.u[1] = f2bf(f0.y);
        af.u[2] = f2bf(f0.z); af.u[3] = f2bf(f0.w);
        af.u[4] = f2bf(f1.x); af.u[5] = f2bf(f1.y);
        af.u[6] = f2bf(f1.z); af.u[7] = f2bf(f1.w);
        acc[m][ci][0] = __builtin_amdgcn_mfma_f32_16x16x32_bf16(af.v, bfr[0].v, acc[m][ci][0], 0, 0, 0);
        acc[m][ci][1] = __builtin_amdgcn_mfma_f32_16x16x32_bf16(af.v, bfr[1].v, acc[m][ci][1], 0, 0, 0);
      }
    }
  }
  __syncthreads();  // matmuls done; h LDS dead -> alias as uv0
  float* uv0s = (float*)hlds;  // [c][e] fp32, 32KB

  if (pr == 0) {
#pragma unroll
    for (int ci = 0; ci < 4; ci++)
#pragma unroll
      for (int j = 0; j < 2; j++) {
        int e = (2 * eq + j) * 16 + lm;
#pragma unroll
        for (int r = 0; r < 4; r++) {
          int c = ci * 16 + lq * 4 + r;
          float T0 = acc[1][ci][j][r];   // w0^T h
          float Q0h = acc[0][ci][j][r];  // q0^T h
          float u0 = Ub[(2 * c) * Dd + e];
          float q0 = Qb[(2 * c) * Dd + e];
          float uv0 = u0 - T0;
          uv0s[c * Dd + e] = uv0;
          Ob[(2 * c) * Dd + e] = q0 * uv0 + Q0h;
        }
      }
  }
  __syncthreads();
  if (pr == 1) {
#pragma unroll
    for (int ci = 0; ci < 4; ci++)
#pragma unroll
      for (int j = 0; j < 2; j++) {
        int e = (2 * eq + j) * 16 + lm;
#pragma unroll
        for (int r = 0; r < 4; r++) {
          int c = ci * 16 + lq * 4 + r;
          float T1 = acc[1][ci][j][r];   // w1^T h
          float Q1h = acc[0][ci][j][r];  // q1^T h
          float u1 = Ub[(2 * c + 1) * Dd + e];
          float q1 = Qb[(2 * c + 1) * Dd + e];
          float uv0 = uv0s[c * Dd + e];
          float uv1 = u1 - T1 - d10s[c] * uv0;
          Ob[(2 * c + 1) * Dd + e] = q1 * uv1 + Q1h + dq1s[c] * uv0;
        }
      }
  }
}

extern "C" void kernel_launch(void* const* d_in, const int* in_sizes, int n_in,
                              void* d_out, int out_size, void* d_ws, size_t ws_size,
                              hipStream_t stream) {
  const float* Q = (const float*)d_in[0];
  const float* W = (const float*)d_in[1];
  const float* U = (const float*)d_in[2];
  const float* h0 = (const float*)d_in[3];
  float* out = (float*)d_out;
  unsigned short* hws = (unsigned short*)d_ws;  // 32*32*16384 bf16 = 32 MiB

  p1_scan<<<32, 512, 0, stream>>>(W, U, h0, hws, out);
  p2_out<<<1024, 512, 0, stream>>>(Q, W, U, hws, out);
}

// Round 2
// 425.866 us; speedup vs baseline: 1.1521x; 1.1521x over previous
//
#include <hip/hip_runtime.h>

// LiZAttention delta-product scan, MI355X — round 2
// B=2 H=16 NC=32 CT=128 (C=64, N_ORDERS=2) D=128
// p1: 32 blocks, register-resident h (thread = column e, dq quarter), W/U rows
//     + d10 prefetched to LDS; norm via pad-129 + rotated-index LDS transpose.
//     Emits h per chunk TRANSPOSED (hT[e][d]) bf16 to ws.
// p2: 1024 blocks; hT staged to LDS stride 136 -> B-frag = single ds_read_b128.

#define Dd 128
#define NCH 32
#define YS 16777216  // ys element count; h_final follows in d_out

typedef __attribute__((ext_vector_type(4))) float floatx4;
typedef __attribute__((ext_vector_type(8))) short short8;

__device__ __forceinline__ unsigned short f2bf(float f) {
  unsigned int u = __float_as_uint(f);
  u += 0x7fffu + ((u >> 16) & 1u);   // RNE
  return (unsigned short)(u >> 16);
}
__device__ __forceinline__ float clampf(float x) {
  return fminf(fmaxf(x, -10000.0f), 10000.0f);
}

// ---------------- Phase 1: sequential h-scan, h in registers ----------------
__global__ __launch_bounds__(512) void p1_scan(const float* __restrict__ W,
    const float* __restrict__ U, const float* __restrict__ h0,
    unsigned short* __restrict__ hws, float* __restrict__ out) {
  __shared__ float wpre[NCH * 2 * Dd];   // [n][order][e] 32KB
  __shared__ float upre[NCH * 2 * Dd];   // 32KB
  __shared__ float d10pre[NCH];
  __shared__ float mvp[2 * 4 * Dd];      // matvec partials [m][dq][e]
  __shared__ float uvs[2 * Dd];          // uv0, uv1
  __shared__ float sqb[Dd * 129];        // h' staging for norm (pad 129)
  __shared__ float psum[Dd * 4];         // [d][eq]
  __shared__ float nrm2[Dd], nrmh[Dd];   // 2/n, n/2

  const int bh = blockIdx.x;
  const int t = threadIdx.x;
  const int e = t & 127, dq = t >> 7;    // thread owns column e, rows dq*32..+31

  // ---- prefetch all W/U c=63 rows (orders 0,1) for all 32 chunks ----
  {
    const float* Wg = W + (size_t)bh * NCH * 16384;
    const float* Ug = U + (size_t)bh * NCH * 16384;
#pragma unroll
    for (int k = 0; k < 4; k++) {
      int idx4 = k * 512 + t;            // float4 idx, 2048 total
      int n = idx4 >> 6;                 // 64 f4 per chunk (2 rows of 32)
      int rem = idx4 & 63;
      int r = rem >> 5, e4 = (rem & 31) * 4;
      size_t g = (size_t)n * 16384 + (size_t)(126 + r) * Dd + e4;
      *(float4*)&wpre[idx4 * 4] = *(const float4*)&Wg[g];
      *(float4*)&upre[idx4 * 4] = *(const float4*)&Ug[g];
    }
  }
  // ---- stage h0 (row-major) into sqb so each thread can gather its column ----
  {
    const float4* hg = (const float4*)(h0 + (size_t)bh * 16384);
#pragma unroll
    for (int k = 0; k < 8; k++) {
      int idx4 = k * 512 + t;            // 4096 total
      float4 v = hg[idx4];
      int d = idx4 >> 5, e4 = (idx4 & 31) * 4;
      sqb[d * 129 + e4 + 0] = v.x;
      sqb[d * 129 + e4 + 1] = v.y;
      sqb[d * 129 + e4 + 2] = v.z;
      sqb[d * 129 + e4 + 3] = v.w;
    }
  }
  __syncthreads();
  // ---- d10[n] = w1 . w0 for all chunks (independent of h) ----
  {
    int n = t >> 4, j = t & 15;
    const float* w0p = &wpre[n * 256 + 8 * j];
    const float* w1p = &wpre[n * 256 + Dd + 8 * j];
    float p = 0.f;
#pragma unroll
    for (int i = 0; i < 8; i++) p += w0p[i] * w1p[i];
    p += __shfl_xor(p, 1, 64);
    p += __shfl_xor(p, 2, 64);
    p += __shfl_xor(p, 4, 64);
    p += __shfl_xor(p, 8, 64);
    if (j == 0) d10pre[n] = p;
  }
  // ---- h column -> registers ----
  float hr[32];
#pragma unroll
  for (int i = 0; i < 32; i++) hr[i] = sqb[(dq * 32 + i) * 129 + e];
  __syncthreads();  // d10pre visible; sqb free for reuse

  unsigned short* hwsb = hws + (size_t)bh * NCH * 16384;
  // ---- chunk 0 state = h0, store transposed bf16 ----
  {
    unsigned int pk[16];
#pragma unroll
    for (int i = 0; i < 16; i++)
      pk[i] = (unsigned)f2bf(hr[2 * i]) | ((unsigned)f2bf(hr[2 * i + 1]) << 16);
    uint4* dst = (uint4*)(hwsb + (size_t)e * Dd + dq * 32);
    dst[0] = make_uint4(pk[0], pk[1], pk[2], pk[3]);
    dst[1] = make_uint4(pk[4], pk[5], pk[6], pk[7]);
    dst[2] = make_uint4(pk[8], pk[9], pk[10], pk[11]);
    dst[3] = make_uint4(pk[12], pk[13], pk[14], pk[15]);
  }

  for (int n = 0; n < NCH; n++) {
    // per-wave broadcast loads of w0/w1 (wave-uniform: all lanes share dq)
    floatx4 w0v[8], w1v[8];
#pragma unroll
    for (int i = 0; i < 8; i++) {
      w0v[i] = *(const floatx4*)&wpre[n * 256 + dq * 32 + 4 * i];
      w1v[i] = *(const floatx4*)&wpre[n * 256 + Dd + dq * 32 + 4 * i];
    }
    // matvec partials: a0 = sum_d w0[d] h[d][e] over this dq quarter
    float a0 = 0.f, a1 = 0.f;
#pragma unroll
    for (int i = 0; i < 8; i++)
#pragma unroll
      for (int j = 0; j < 4; j++) {
        float h = hr[4 * i + j];
        a0 += w0v[i][j] * h;
        a1 += w1v[i][j] * h;
      }
    mvp[dq * Dd + e] = a0;
    mvp[512 + dq * Dd + e] = a1;
    __syncthreads();                                   // S1
    if (t < Dd) {
      float t0 = mvp[t] + mvp[Dd + t] + mvp[2 * Dd + t] + mvp[3 * Dd + t];
      float t1 = mvp[512 + t] + mvp[512 + Dd + t] + mvp[512 + 2 * Dd + t] +
                 mvp[512 + 3 * Dd + t];
      float u0 = upre[n * 256 + t];
      float u1 = upre[n * 256 + Dd + t];
      float uv0 = u0 - t0;
      float uv1 = u1 - t1 - d10pre[n] * uv0;
      uvs[t] = uv0;
      uvs[Dd + t] = uv1;
    }
    __syncthreads();                                   // S2
    const float uv0 = uvs[e], uv1 = uvs[Dd + e];
    // rank-2 update in registers; write h' for row-norm
#pragma unroll
    for (int i = 0; i < 8; i++)
#pragma unroll
      for (int j = 0; j < 4; j++) {
        int ii = 4 * i + j;
        float s = clampf(clampf(hr[ii] + w0v[i][j] * uv0) + w1v[i][j] * uv1);
        hr[ii] = s;
        sqb[(dq * 32 + ii) * 129 + e] = s;
      }
    __syncthreads();                                   // S3
    // row sum-of-squares: thread = (row d2, e-quarter eq); rotated index ->
    // bank = (d2 + i + 8eq)%32, conflict-free
    {
      const int d2 = t >> 2, eq = t & 3;
      float acc = 0.f;
#pragma unroll
      for (int i = 0; i < 32; i++) {
        int ii = (i + 8 * eq) & 31;
        float v = sqb[d2 * 129 + eq * 32 + ii];
        acc += v * v;
      }
      psum[d2 * 4 + eq] = acc;
    }
    __syncthreads();                                   // S4
    if (t < Dd) {
      floatx4 p = *(const floatx4*)&psum[t * 4];
      float nd = sqrtf(p[0] + p[1] + p[2] + p[3]) + 1e-6f;
      nrm2[t] = 2.0f / nd;
      nrmh[t] = 0.5f * nd;
    }
    __syncthreads();                                   // S5
    // gelu_norm in registers: h = (n/2) * x * sigmoid(1.59577(x + .044715x^3)), x = 2h/n
    floatx4 r2v[8], hnv[8];
#pragma unroll
    for (int i = 0; i < 8; i++) {
      r2v[i] = *(const floatx4*)&nrm2[dq * 32 + 4 * i];
      hnv[i] = *(const floatx4*)&nrmh[dq * 32 + 4 * i];
    }
#pragma unroll
    for (int i = 0; i < 8; i++)
#pragma unroll
      for (int j = 0; j < 4; j++) {
        int ii = 4 * i + j;
        float x = hr[ii] * r2v[i][j];
        float x2 = x * x;
        float aa = x * fmaf(0.071354816f, x2, 1.59576912f);
        float ex = __expf(-aa);
        float g = x / (1.0f + ex);
        hr[ii] = hnv[i][j] * g;
      }
    if (n < NCH - 1) {
      unsigned int pk[16];
#pragma unroll
      for (int i = 0; i < 16; i++)
        pk[i] = (unsigned)f2bf(hr[2 * i]) | ((unsigned)f2bf(hr[2 * i + 1]) << 16);
      uint4* dst = (uint4*)(hwsb + (size_t)(n + 1) * 16384 + (size_t)e * Dd + dq * 32);
      dst[0] = make_uint4(pk[0], pk[1], pk[2], pk[3]);
      dst[1] = make_uint4(pk[4], pk[5], pk[6], pk[7]);
      dst[2] = make_uint4(pk[8], pk[9], pk[10], pk[11]);
      dst[3] = make_uint4(pk[12], pk[13], pk[14], pk[15]);
    } else {
      float* ob = out + YS + (size_t)bh * 16384;
#pragma unroll
      for (int i = 0; i < 32; i++) ob[(dq * 32 + i) * Dd + e] = hr[i];
    }
    // no trailing sync needed: next-iter LDS writes are separated from this
    // iter's readers by >=1 barrier (verified per-buffer)
  }
}

// ---------------- Phase 2: per-tile outputs via MFMA ----------------
// wave w (of 8): pair p=w>>2 (0:{Q0,W0}, 1:{Q1,W1}), e-quarter eq=w&3
// 16x16x32 bf16 MFMA: A[m=lane&15][k=8*(lane>>4)+i]; B[k][n=lane&15];
//                     C/D: row=4*(lane>>4)+reg, col=lane&15   [m89/m91]
__global__ __launch_bounds__(512) void p2_out(const float* __restrict__ Q,
    const float* __restrict__ W, const float* __restrict__ U,
    const unsigned short* __restrict__ hws, float* __restrict__ out) {
  __shared__ unsigned short hT[Dd * 136];  // transposed h, pad 136 (16B-aligned rows)
  __shared__ float d10s[64], dq1s[64];
  __shared__ float dps[512];

  const int bid = blockIdx.x;
  const int n = bid & 31, bh = bid >> 5;
  const size_t base = (size_t)(bh * NCH + n) * 16384;
  const float* Qb = Q + base;
  const float* Wb = W + base;
  const float* Ub = U + base;
  float* Ob = out + base;
  const int t = threadIdx.x;

  // stage hT (global e-major, stride 128) -> LDS stride 136
  {
    const uint4* src = (const uint4*)(hws + base);
#pragma unroll
    for (int i = 0; i < 4; i++) {
      int idx = t + i * 512;             // uint4 idx, 2048 total
      uint4 v = src[idx];
      int e = idx >> 4, j = idx & 15;
      *(uint4*)&hT[e * 136 + j * 8] = v;
    }
  }
  // per-c dots: d10[c]=w1.w0, dq1[c]=q1.w0  (fp32 from global)
  {
    int which = t >> 8, tt = t & 255;
    int c = tt >> 2, part = tt & 3;
    const float* ar = (which ? Qb : Wb) + (2 * c + 1) * Dd + part * 32;
    const float* w0r = Wb + (2 * c) * Dd + part * 32;
    float s = 0.f;
#pragma unroll
    for (int i = 0; i < 32; i++) s += ar[i] * w0r[i];
    dps[which * 256 + tt] = s;
  }
  __syncthreads();
  if (t < 128) {
    int which = t >> 6, c = t & 63;
    const float* p = dps + which * 256 + c * 4;
    float s = p[0] + p[1] + p[2] + p[3];
    (which ? dq1s : d10s)[c] = s;
  }

  const int wv = t >> 6, l = t & 63;
  const int pr = wv >> 2, eq = wv & 3;
  const int lm = l & 15, lq = l >> 4;

  floatx4 acc[2][4][2];  // [mat 0=Q_p,1=W_p][ctile][etile]
#pragma unroll
  for (int m = 0; m < 2; m++)
#pragma unroll
    for (int ci = 0; ci < 4; ci++)
#pragma unroll
      for (int j = 0; j < 2; j++) acc[m][ci][j] = (floatx4){0.f, 0.f, 0.f, 0.f};

  for (int kc = 0; kc < 4; kc++) {
    const int k0 = kc * 32;
    short8 bfr[2];
#pragma unroll
    for (int j = 0; j < 2; j++) {
      int ee = (2 * eq + j) * 16 + lm;
      bfr[j] = *(const short8*)&hT[ee * 136 + k0 + 8 * lq];  // one ds_read_b128
    }
#pragma unroll
    for (int m = 0; m < 2; m++) {
      const float* X = m ? Wb : Qb;
#pragma unroll
      for (int ci = 0; ci < 4; ci++) {
        int c = ci * 16 + lm;
        const float* row = X + (size_t)(2 * c + pr) * Dd + k0 + 8 * lq;
        float4 f0 = ((const float4*)row)[0];
        float4 f1 = ((const float4*)row)[1];
        union { short8 v; unsigned short u[8]; } af;
        af.u[0] = f2bf(f0.x); af.u[1] = f2bf(f0.y);
        af.u[2] = f2bf(f0.z); af.u[3] = f2bf(f0.w);
        af.u[4] = f2bf(f1.x); af.u[5] = f2bf(f1.y);
        af.u[6] = f2bf(f1.z); af.u[7] = f2bf(f1.w);
        acc[m][ci][0] = __builtin_amdgcn_mfma_f32_16x16x32_bf16(af.v, bfr[0], acc[m][ci][0], 0, 0, 0);
        acc[m][ci][1] = __builtin_amdgcn_mfma_f32_16x16x32_bf16(af.v, bfr[1], acc[m][ci][1], 0, 0, 0);
      }
    }
  }
  __syncthreads();  // matmuls done; hT LDS dead -> alias as uv0 (fp32 64x128)
  float* uv0s = (float*)hT;

  if (pr == 0) {
#pragma unroll
    for (int ci = 0; ci < 4; ci++)
#pragma unroll
      for (int j = 0; j < 2; j++) {
        int ee = (2 * eq + j) * 16 + lm;
#pragma unroll
        for (int r = 0; r < 4; r++) {
          int c = ci * 16 + lq * 4 + r;
          float T0 = acc[1][ci][j][r];   // w0^T h
          float Q0h = acc[0][ci][j][r];  // q0^T h
          float u0 = Ub[(2 * c) * Dd + ee];
          float q0 = Qb[(2 * c) * Dd + ee];
          float uv0 = u0 - T0;
          uv0s[c * Dd + ee] = uv0;
          Ob[(2 * c) * Dd + ee] = q0 * uv0 + Q0h;
        }
      }
  }
  __syncthreads();
  if (pr == 1) {
#pragma unroll
    for (int ci = 0; ci < 4; ci++)
#pragma unroll
      for (int j = 0; j < 2; j++) {
        int ee = (2 * eq + j) * 16 + lm;
#pragma unroll
        for (int r = 0; r < 4; r++) {
          int c = ci * 16 + lq * 4 + r;
          float T1 = acc[1][ci][j][r];   // w1^T h
          float Q1h = acc[0][ci][j][r];  // q1^T h
          float u1 = Ub[(2 * c + 1) * Dd + ee];
          float q1 = Qb[(2 * c + 1) * Dd + ee];
          float uv0 = uv0s[c * Dd + ee];
          float uv1 = u1 - T1 - d10s[c] * uv0;
          Ob[(2 * c + 1) * Dd + ee] = q1 * uv1 + Q1h + dq1s[c] * uv0;
        }
      }
  }
}

extern "C" void kernel_launch(void* const* d_in, const int* in_sizes, int n_in,
                              void* d_out, int out_size, void* d_ws, size_t ws_size,
                              hipStream_t stream) {
  const float* Q = (const float*)d_in[0];
  const float* W = (const float*)d_in[1];
  const float* U = (const float*)d_in[2];
  const float* h0 = (const float*)d_in[3];
  float* out = (float*)d_out;
  unsigned short* hws = (unsigned short*)d_ws;  // 32*32*16384 bf16 = 32 MiB, transposed [e][d]

  p1_scan<<<32, 512, 0, stream>>>(W, U, h0, hws, out);
  p2_out<<<1024, 512, 0, stream>>>(Q, W, U, hws, out);
}